// Round 2
// baseline (1139.331 us; speedup 1.0000x reference)
//
#include <hip/hip_runtime.h>
#include <hip/hip_bf16.h>

#define NN 100000
#define EE 1600000

constexpr int SCAN_BLK = 1024;                       // elements per scan block (256 thr * 4)
constexpr int NB_SCAN  = (NN + SCAN_BLK - 1) / SCAN_BLK;  // 98

// ---------------- CSR build ----------------

__global__ void zero_int(int* __restrict__ p, int n) {
    int i = blockIdx.x * 256 + threadIdx.x;
    if (i < n) p[i] = 0;
}

__global__ void hist_k(const int* __restrict__ ei, int* __restrict__ deg) {
    int e = blockIdx.x * 256 + threadIdx.x;
    if (e < EE) {
        int s = ei[e], d = ei[EE + e];
        if (s != d) atomicAdd(&deg[d], 1);   // original self-loops are masked out entirely
    }
}

__global__ void sum_blocks(const int* __restrict__ deg, int* __restrict__ partials) {
    __shared__ int sh[256];
    int t = threadIdx.x;
    int base = blockIdx.x * SCAN_BLK + t * 4;
    int s = 0;
    #pragma unroll
    for (int k = 0; k < 4; ++k) { int i = base + k; if (i < NN) s += deg[i]; }
    sh[t] = s; __syncthreads();
    for (int off = 128; off > 0; off >>= 1) {
        if (t < off) sh[t] += sh[t + off];
        __syncthreads();
    }
    if (t == 0) partials[blockIdx.x] = sh[0];
}

__global__ void scan_partials(int* __restrict__ partials) {
    if (threadIdx.x == 0 && blockIdx.x == 0) {
        int run = 0;
        for (int i = 0; i < NB_SCAN; ++i) { int v = partials[i]; partials[i] = run; run += v; }
    }
}

__global__ void scan_final(const int* __restrict__ deg, const int* __restrict__ partials,
                           int* __restrict__ rowptr, int* __restrict__ cursor) {
    __shared__ int sh[256];
    int t = threadIdx.x;
    int base = blockIdx.x * SCAN_BLK + t * 4;
    int v[4]; int s = 0;
    #pragma unroll
    for (int k = 0; k < 4; ++k) { int i = base + k; v[k] = (i < NN) ? deg[i] : 0; s += v[k]; }
    sh[t] = s; __syncthreads();
    // Hillis-Steele inclusive scan over 256 thread sums
    for (int off = 1; off < 256; off <<= 1) {
        int tmp = (t >= off) ? sh[t - off] : 0;
        __syncthreads();
        sh[t] += tmp;
        __syncthreads();
    }
    int pref = partials[blockIdx.x] + sh[t] - s;   // exclusive prefix for this thread's chunk
    #pragma unroll
    for (int k = 0; k < 4; ++k) {
        int i = base + k;
        if (i < NN) {
            rowptr[i] = pref; cursor[i] = pref; pref += v[k];
            if (i == NN - 1) rowptr[NN] = pref;
        }
    }
}

__global__ void scatter_k(const int* __restrict__ ei, int* __restrict__ cursor,
                          int* __restrict__ col) {
    int e = blockIdx.x * 256 + threadIdx.x;
    if (e < EE) {
        int s = ei[e], d = ei[EE + e];
        if (s != d) { int p = atomicAdd(&cursor[d], 1); col[p] = s; }
    }
}

// ---------------- GEMM (h = x @ W) + per-node attention scalars ----------------
// K = in-dim, M = out-dim (= H*C), H = heads. One thread per (node, out-channel).

template<int K, int M, int H>
__global__ void gemm_scal(const float* __restrict__ xin,
                          const float* __restrict__ W,
                          const float* __restrict__ att,
                          float* __restrict__ hbuf,
                          float* __restrict__ sdst, float* __restrict__ ssrc) {
    constexpr int NPB = 256 / M;     // nodes per block
    constexpr int C   = M / H;       // channels per head
    __shared__ float Wl[K * M];
    __shared__ float Xl[NPB * K];
    int tid = threadIdx.x;
    for (int i = tid; i < K * M; i += 256) Wl[i] = W[i];
    int node0 = blockIdx.x * NPB;    // NN divisible by NPB (4 or 8)
    for (int i = tid; i < NPB * K; i += 256) Xl[i] = xin[(size_t)node0 * K + i];
    __syncthreads();

    int m = tid % M, ln = tid / M;
    int node = node0 + ln;
    const float* xr = &Xl[ln * K];
    float acc = 0.f;
    #pragma unroll 8
    for (int k = 0; k < K; ++k) acc = fmaf(xr[k], Wl[k * M + m], acc);
    hbuf[(size_t)node * M + m] = acc;

    // s_dst[n,h] = sum_c h[n,h,c]*att[h, c];  s_src uses att[h, C+c]
    int head = m / C, c = m % C;
    float pd = acc * att[head * 2 * C + c];
    float ps = acc * att[head * 2 * C + C + c];
    #pragma unroll
    for (int off = 1; off < C; off <<= 1) {
        pd += __shfl_xor(pd, off, 64);
        ps += __shfl_xor(ps, off, 64);
    }
    if (c == 0) { sdst[node * H + head] = pd; ssrc[node * H + head] = ps; }
}

// ---------------- Aggregation: one wave per node ----------------
// lane < CT: channel accumulator; lanes 0..H-1 also compute per-head exp terms.
// out = (sum_e ex_e * h[src_e]) / (sum_e ex_e) + bias, then ELU (layers 1-2 store f32)
// or plain f32 store (layer 3 -> d_out).

template<int CT, int H, bool ELU_OUT>
__global__ void agg_k(const int* __restrict__ rowptr, const int* __restrict__ col,
                      const float* __restrict__ sdst, const float* __restrict__ ssrc,
                      const float* __restrict__ hbuf, const float* __restrict__ bias,
                      float* __restrict__ output) {
    constexpr int C = CT / H;
    int lane = threadIdx.x & 63;
    int node = blockIdx.x * (blockDim.x >> 6) + (threadIdx.x >> 6);
    if (node >= NN) return;

    int head = (lane < CT) ? (lane / C) : 0;
    float sd = (lane < H) ? sdst[node * H + lane] : 0.f;
    int start = rowptr[node], end = rowptr[node + 1];

    float acc = 0.f, dsum = 0.f;
    for (int j = start; j < end; ++j) {
        int s = col[j];
        float e = 0.f;
        if (lane < H) {
            float a = sd + ssrc[s * H + lane];
            a = (a >= 0.f) ? a : 0.2f * a;     // leaky_relu
            e = __expf(a);
            dsum += e;
        }
        float exc = __shfl(e, head, 64);
        if (lane < CT) acc += exc * hbuf[(size_t)s * CT + lane];
    }
    // fresh self-loop (never masked)
    {
        float e = 0.f;
        if (lane < H) {
            float a = sd + ssrc[node * H + lane];
            a = (a >= 0.f) ? a : 0.2f * a;
            e = __expf(a);
            dsum += e;
        }
        float exc = __shfl(e, head, 64);
        if (lane < CT) acc += exc * hbuf[(size_t)node * CT + lane];
    }
    float den = __shfl(dsum, head, 64);
    if (lane < CT) {
        float v = acc / den + bias[lane];
        if (ELU_OUT) v = (v > 0.f) ? v : expm1f(v);     // ELU(alpha=1)
        output[(size_t)node * CT + lane] = v;
    }
}

// ---------------- launch ----------------

extern "C" void kernel_launch(void* const* d_in, const int* in_sizes, int n_in,
                              void* d_out, int out_size, void* d_ws, size_t ws_size,
                              hipStream_t stream) {
    const float* x    = (const float*)d_in[0];
    const int*   ei   = (const int*)d_in[1];
    const float* W1   = (const float*)d_in[2];
    const float* att1 = (const float*)d_in[3];
    const float* b1   = (const float*)d_in[4];
    const float* W2   = (const float*)d_in[5];
    const float* att2 = (const float*)d_in[6];
    const float* b2   = (const float*)d_in[7];
    const float* W3   = (const float*)d_in[8];
    const float* att3 = (const float*)d_in[9];
    const float* b3   = (const float*)d_in[10];
    float* out = (float*)d_out;

    char* p = (char*)d_ws;
    auto alloc = [&](size_t bytes) -> void* {
        void* r = (void*)p;
        p += (bytes + 255) & ~(size_t)255;
        return r;
    };
    int*   rowptr   = (int*)alloc((NN + 1) * sizeof(int));
    int*   cursor   = (int*)alloc(NN * sizeof(int));
    int*   partials = (int*)alloc(NB_SCAN * sizeof(int));
    int*   col      = (int*)alloc(EE * sizeof(int));
    float* sdst     = (float*)alloc((size_t)NN * 8 * sizeof(float));
    float* ssrc     = (float*)alloc((size_t)NN * 8 * sizeof(float));
    float* Hb       = (float*)alloc((size_t)NN * 64 * sizeof(float));
    float* Fb       = (float*)alloc((size_t)NN * 64 * sizeof(float));

    // --- CSR build (dst-grouped, original non-self edges only) ---
    zero_int<<<(NN + 255) / 256, 256, 0, stream>>>(cursor, NN);
    hist_k<<<EE / 256, 256, 0, stream>>>(ei, cursor);
    sum_blocks<<<NB_SCAN, 256, 0, stream>>>(cursor, partials);
    scan_partials<<<1, 64, 0, stream>>>(partials);
    scan_final<<<NB_SCAN, 256, 0, stream>>>(cursor, partials, rowptr, cursor);
    scatter_k<<<EE / 256, 256, 0, stream>>>(ei, cursor, col);

    // --- Layer 1: x[N,128] -> h[N,64]; H=8, C=8; ELU out -> Fb ---
    gemm_scal<128, 64, 8><<<NN / 4, 256, 0, stream>>>(x, W1, att1, Hb, sdst, ssrc);
    agg_k<64, 8, true><<<(NN + 3) / 4, 256, 0, stream>>>(rowptr, col, sdst, ssrc, Hb, b1, Fb);

    // --- Layer 2: Fb[N,64] -> h[N,64]; H=8, C=8; ELU out -> Fb ---
    gemm_scal<64, 64, 8><<<NN / 4, 256, 0, stream>>>(Fb, W2, att2, Hb, sdst, ssrc);
    agg_k<64, 8, true><<<(NN + 3) / 4, 256, 0, stream>>>(rowptr, col, sdst, ssrc, Hb, b2, Fb);

    // --- Layer 3: Fb[N,64] -> h[N,32]; H=1, C=32; no ELU, f32 out -> d_out ---
    gemm_scal<64, 32, 1><<<NN / 8, 256, 0, stream>>>(Fb, W3, att3, Hb, sdst, ssrc);
    agg_k<32, 1, false><<<(NN + 3) / 4, 256, 0, stream>>>(rowptr, col, sdst, ssrc, Hb, b3, out);
}

// Round 3
// 777.262 us; speedup vs baseline: 1.4658x; 1.4658x over previous
//
#include <hip/hip_runtime.h>
#include <hip/hip_bf16.h>

#define NN 100000
#define EE 1600000

constexpr int SCAN_BLK = 1024;                       // elements per scan block (256 thr * 4)
constexpr int NB_SCAN  = (NN + SCAN_BLK - 1) / SCAN_BLK;  // 98

// ---------------- CSR build ----------------

__global__ void zero_int(int* __restrict__ p, int n) {
    int i = blockIdx.x * 256 + threadIdx.x;
    if (i < n) p[i] = 0;
}

__global__ void hist_k(const int* __restrict__ ei, int* __restrict__ deg) {
    int e = blockIdx.x * 256 + threadIdx.x;
    if (e < EE) {
        int s = ei[e], d = ei[EE + e];
        if (s != d) atomicAdd(&deg[d], 1);   // original self-loops are masked out entirely
    }
}

__global__ void sum_blocks(const int* __restrict__ deg, int* __restrict__ partials) {
    __shared__ int sh[256];
    int t = threadIdx.x;
    int base = blockIdx.x * SCAN_BLK + t * 4;
    int s = 0;
    #pragma unroll
    for (int k = 0; k < 4; ++k) { int i = base + k; if (i < NN) s += deg[i]; }
    sh[t] = s; __syncthreads();
    for (int off = 128; off > 0; off >>= 1) {
        if (t < off) sh[t] += sh[t + off];
        __syncthreads();
    }
    if (t == 0) partials[blockIdx.x] = sh[0];
}

__global__ void scan_partials(int* __restrict__ partials) {
    __shared__ int sh[128];
    int t = threadIdx.x;
    int v = (t < NB_SCAN) ? partials[t] : 0;
    sh[t] = v;
    __syncthreads();
    for (int off = 1; off < 128; off <<= 1) {
        int tmp = (t >= off) ? sh[t - off] : 0;
        __syncthreads();
        sh[t] += tmp;
        __syncthreads();
    }
    if (t < NB_SCAN) partials[t] = sh[t] - v;   // exclusive prefix
}

__global__ void scan_final(const int* __restrict__ deg, const int* __restrict__ partials,
                           int* __restrict__ rowptr, int* __restrict__ cursor) {
    __shared__ int sh[256];
    int t = threadIdx.x;
    int base = blockIdx.x * SCAN_BLK + t * 4;
    int v[4]; int s = 0;
    #pragma unroll
    for (int k = 0; k < 4; ++k) { int i = base + k; v[k] = (i < NN) ? deg[i] : 0; s += v[k]; }
    sh[t] = s; __syncthreads();
    // Hillis-Steele inclusive scan over 256 thread sums
    for (int off = 1; off < 256; off <<= 1) {
        int tmp = (t >= off) ? sh[t - off] : 0;
        __syncthreads();
        sh[t] += tmp;
        __syncthreads();
    }
    int pref = partials[blockIdx.x] + sh[t] - s;   // exclusive prefix for this thread's chunk
    #pragma unroll
    for (int k = 0; k < 4; ++k) {
        int i = base + k;
        if (i < NN) {
            rowptr[i] = pref; cursor[i] = pref; pref += v[k];
            if (i == NN - 1) rowptr[NN] = pref;
        }
    }
}

__global__ void scatter_k(const int* __restrict__ ei, int* __restrict__ cursor,
                          int* __restrict__ col) {
    int e = blockIdx.x * 256 + threadIdx.x;
    if (e < EE) {
        int s = ei[e], d = ei[EE + e];
        if (s != d) { int p = atomicAdd(&cursor[d], 1); col[p] = s; }
    }
}

// ---------------- GEMM (h = x @ W) + per-node attention scalars ----------------
// K = in-dim, M = out-dim (= H*C), H = heads. One thread per (node, out-channel).
// W staged in LDS as per-column float4 quads -> ds_read_b128 inner loop.

template<int K, int M, int H>
__global__ void gemm_scal(const float* __restrict__ xin,
                          const float* __restrict__ W,
                          const float* __restrict__ att,
                          float* __restrict__ hbuf,
                          float* __restrict__ sdst, float* __restrict__ ssrc) {
    constexpr int NPB = 256 / M;     // nodes per block
    constexpr int C   = M / H;       // channels per head
    constexpr int K4  = K / 4;
    __shared__ float4 Wq[K4 * M];    // Wq[k4*M + m] = {W[4k4][m], W[4k4+1][m], ...}
    __shared__ float4 Xq[NPB * K4];
    int tid = threadIdx.x;
    for (int i = tid; i < K * M; i += 256) {
        int k = i / M, m = i % M;
        ((float*)&Wq[(k >> 2) * M + m])[k & 3] = W[i];
    }
    int node0 = blockIdx.x * NPB;    // NN divisible by NPB (4 or 8)
    for (int i = tid; i < NPB * K4; i += 256)
        Xq[i] = ((const float4*)xin)[(size_t)node0 * K4 + i];
    __syncthreads();

    int m = tid % M, ln = tid / M;
    int node = node0 + ln;
    float acc = 0.f;
    #pragma unroll
    for (int k4 = 0; k4 < K4; ++k4) {
        float4 w  = Wq[k4 * M + m];
        float4 xv = Xq[ln * K4 + k4];
        acc = fmaf(xv.x, w.x, acc);
        acc = fmaf(xv.y, w.y, acc);
        acc = fmaf(xv.z, w.z, acc);
        acc = fmaf(xv.w, w.w, acc);
    }
    hbuf[(size_t)node * M + m] = acc;

    // s_dst[n,h] = sum_c h[n,h,c]*att[h, c];  s_src uses att[h, C+c]
    int head = m / C, c = m % C;
    float pd = acc * att[head * 2 * C + c];
    float ps = acc * att[head * 2 * C + C + c];
    #pragma unroll
    for (int off = 1; off < C; off <<= 1) {
        pd += __shfl_xor(pd, off, 64);
        ps += __shfl_xor(ps, off, 64);
    }
    if (c == 0) { sdst[node * H + head] = pd; ssrc[node * H + head] = ps; }
}

// ---------------- Aggregation: one wave per node, 4-edge unroll ----------------
// G = 64/CT gather slots per load instruction. Lanes < 4H each compute one exp
// (edge g = lane/H, head lane%H). h-row gathers issue 4/G independent loads.

template<int CT, int H, bool ELU_OUT>
__global__ void agg_k(const int* __restrict__ rowptr, const int* __restrict__ col,
                      const float* __restrict__ sdst, const float* __restrict__ ssrc,
                      const float* __restrict__ hbuf, const float* __restrict__ bias,
                      float* __restrict__ output) {
    constexpr int C = CT / H;
    constexpr int G = 64 / CT;          // edge slots per gather instruction (1 or 2)
    int lane = threadIdx.x & 63;
    int node = blockIdx.x * (blockDim.x >> 6) + (threadIdx.x >> 6);
    if (node >= NN) return;

    int c  = lane % CT;                 // channel handled by this lane
    int p  = lane / CT;                 // gather slot (0..G-1)
    int hh = c / C;                     // head of channel c
    int h  = lane % H;                  // head for exp lanes
    float sd = (lane < 4 * H) ? sdst[node * H + h] : 0.f;

    int start = rowptr[node], end = rowptr[node + 1];
    float acc = 0.f, dsum = 0.f;

    int j = start;
    for (; j + 4 <= end; j += 4) {
        int s0 = col[j], s1 = col[j + 1], s2 = col[j + 2], s3 = col[j + 3];
        float e = 0.f;
        if (lane < 4 * H) {
            int g = lane / H;           // edge slot for this exp lane
            int sg = (g == 0) ? s0 : (g == 1) ? s1 : (g == 2) ? s2 : s3;
            float a = sd + ssrc[sg * H + h];
            a = (a >= 0.f) ? a : 0.2f * a;      // leaky_relu
            e = __expf(a);
            dsum += e;
        }
        float hv[4 / G];
        #pragma unroll
        for (int t = 0; t < 4 / G; ++t) {
            int eidx = t * G + p;
            int sg = (eidx == 0) ? s0 : (eidx == 1) ? s1 : (eidx == 2) ? s2 : s3;
            hv[t] = hbuf[(size_t)sg * CT + c];
        }
        #pragma unroll
        for (int t = 0; t < 4 / G; ++t) {
            int eidx = t * G + p;
            float ex = __shfl(e, eidx * H + hh, 64);
            acc = fmaf(ex, hv[t], acc);
        }
    }
    // remainder edges + fresh self-loop (last iteration), one at a time on slot p==0
    int rem = end - j;
    for (int r = 0; r <= rem; ++r) {
        int s = (r == rem) ? node : col[j + r];
        float e = 0.f;
        if (lane < H) {
            float a = sd + ssrc[s * H + h];
            a = (a >= 0.f) ? a : 0.2f * a;
            e = __expf(a);
            dsum += e;
        }
        float ex = __shfl(e, hh, 64);
        if (p == 0) acc = fmaf(ex, hbuf[(size_t)s * CT + c], acc);
    }
    // reduce dsum over the 4 edge-slots: lane (g*H + h) -> sum over g
    dsum += __shfl_xor(dsum, H, 64);
    dsum += __shfl_xor(dsum, 2 * H, 64);
    float den = __shfl(dsum, hh, 64);
    // reduce acc over gather slots
    if (G == 2) acc += __shfl_xor(acc, 32, 64);
    if (lane < CT) {
        float v = acc / den + bias[c];
        if (ELU_OUT) v = (v > 0.f) ? v : expm1f(v);     // ELU(alpha=1)
        output[(size_t)node * CT + c] = v;
    }
}

// ---------------- launch ----------------

extern "C" void kernel_launch(void* const* d_in, const int* in_sizes, int n_in,
                              void* d_out, int out_size, void* d_ws, size_t ws_size,
                              hipStream_t stream) {
    const float* x    = (const float*)d_in[0];
    const int*   ei   = (const int*)d_in[1];
    const float* W1   = (const float*)d_in[2];
    const float* att1 = (const float*)d_in[3];
    const float* b1   = (const float*)d_in[4];
    const float* W2   = (const float*)d_in[5];
    const float* att2 = (const float*)d_in[6];
    const float* b2   = (const float*)d_in[7];
    const float* W3   = (const float*)d_in[8];
    const float* att3 = (const float*)d_in[9];
    const float* b3   = (const float*)d_in[10];
    float* out = (float*)d_out;

    char* p = (char*)d_ws;
    auto alloc = [&](size_t bytes) -> void* {
        void* r = (void*)p;
        p += (bytes + 255) & ~(size_t)255;
        return r;
    };
    int*   rowptr   = (int*)alloc((NN + 1) * sizeof(int));
    int*   cursor   = (int*)alloc(NN * sizeof(int));
    int*   partials = (int*)alloc(NB_SCAN * sizeof(int));
    int*   col      = (int*)alloc(EE * sizeof(int));
    float* sdst     = (float*)alloc((size_t)NN * 8 * sizeof(float));
    float* ssrc     = (float*)alloc((size_t)NN * 8 * sizeof(float));
    float* Hb       = (float*)alloc((size_t)NN * 64 * sizeof(float));
    float* Fb       = (float*)alloc((size_t)NN * 64 * sizeof(float));

    // --- CSR build (dst-grouped, original non-self edges only) ---
    zero_int<<<(NN + 255) / 256, 256, 0, stream>>>(cursor, NN);
    hist_k<<<EE / 256, 256, 0, stream>>>(ei, cursor);
    sum_blocks<<<NB_SCAN, 256, 0, stream>>>(cursor, partials);
    scan_partials<<<1, 128, 0, stream>>>(partials);
    scan_final<<<NB_SCAN, 256, 0, stream>>>(cursor, partials, rowptr, cursor);
    scatter_k<<<EE / 256, 256, 0, stream>>>(ei, cursor, col);

    // --- Layer 1: x[N,128] -> h[N,64]; H=8, C=8; ELU out -> Fb ---
    gemm_scal<128, 64, 8><<<NN / 4, 256, 0, stream>>>(x, W1, att1, Hb, sdst, ssrc);
    agg_k<64, 8, true><<<(NN + 3) / 4, 256, 0, stream>>>(rowptr, col, sdst, ssrc, Hb, b1, Fb);

    // --- Layer 2: Fb[N,64] -> h[N,64]; H=8, C=8; ELU out -> Fb ---
    gemm_scal<64, 64, 8><<<NN / 4, 256, 0, stream>>>(Fb, W2, att2, Hb, sdst, ssrc);
    agg_k<64, 8, true><<<(NN + 3) / 4, 256, 0, stream>>>(rowptr, col, sdst, ssrc, Hb, b2, Fb);

    // --- Layer 3: Fb[N,64] -> h[N,32]; H=1, C=32; no ELU, f32 out -> d_out ---
    gemm_scal<64, 32, 1><<<NN / 8, 256, 0, stream>>>(Fb, W3, att3, Hb, sdst, ssrc);
    agg_k<32, 1, false><<<(NN + 3) / 4, 256, 0, stream>>>(rowptr, col, sdst, ssrc, Hb, b3, out);
}

// Round 4
// 678.729 us; speedup vs baseline: 1.6786x; 1.1452x over previous
//
#include <hip/hip_runtime.h>
#include <hip/hip_bf16.h>

#define NN 100000
#define EE 1600000

constexpr int SCAN_BLK = 1024;                       // elements per scan block (256 thr * 4)
constexpr int NB_SCAN  = (NN + SCAN_BLK - 1) / SCAN_BLK;  // 98

// ---------------- CSR build ----------------

__global__ void zero_int(int* __restrict__ p, int n) {
    int i = blockIdx.x * 256 + threadIdx.x;
    if (i < n) p[i] = 0;
}

__global__ void hist_k(const int* __restrict__ ei, int* __restrict__ deg) {
    int e = blockIdx.x * 256 + threadIdx.x;
    if (e < EE) {
        int s = ei[e], d = ei[EE + e];
        if (s != d) atomicAdd(&deg[d], 1);   // original self-loops are masked out entirely
    }
}

__global__ void sum_blocks(const int* __restrict__ deg, int* __restrict__ partials) {
    __shared__ int sh[256];
    int t = threadIdx.x;
    int base = blockIdx.x * SCAN_BLK + t * 4;
    int s = 0;
    #pragma unroll
    for (int k = 0; k < 4; ++k) { int i = base + k; if (i < NN) s += deg[i]; }
    sh[t] = s; __syncthreads();
    for (int off = 128; off > 0; off >>= 1) {
        if (t < off) sh[t] += sh[t + off];
        __syncthreads();
    }
    if (t == 0) partials[blockIdx.x] = sh[0];
}

__global__ void scan_partials(int* __restrict__ partials) {
    __shared__ int sh[128];
    int t = threadIdx.x;
    int v = (t < NB_SCAN) ? partials[t] : 0;
    sh[t] = v;
    __syncthreads();
    for (int off = 1; off < 128; off <<= 1) {
        int tmp = (t >= off) ? sh[t - off] : 0;
        __syncthreads();
        sh[t] += tmp;
        __syncthreads();
    }
    if (t < NB_SCAN) partials[t] = sh[t] - v;   // exclusive prefix
}

__global__ void scan_final(const int* __restrict__ deg, const int* __restrict__ partials,
                           int* __restrict__ rowptr, int* __restrict__ cursor) {
    __shared__ int sh[256];
    int t = threadIdx.x;
    int base = blockIdx.x * SCAN_BLK + t * 4;
    int v[4]; int s = 0;
    #pragma unroll
    for (int k = 0; k < 4; ++k) { int i = base + k; v[k] = (i < NN) ? deg[i] : 0; s += v[k]; }
    sh[t] = s; __syncthreads();
    // Hillis-Steele inclusive scan over 256 thread sums
    for (int off = 1; off < 256; off <<= 1) {
        int tmp = (t >= off) ? sh[t - off] : 0;
        __syncthreads();
        sh[t] += tmp;
        __syncthreads();
    }
    int pref = partials[blockIdx.x] + sh[t] - s;   // exclusive prefix for this thread's chunk
    #pragma unroll
    for (int k = 0; k < 4; ++k) {
        int i = base + k;
        if (i < NN) {
            rowptr[i] = pref; cursor[i] = pref; pref += v[k];
            if (i == NN - 1) rowptr[NN] = pref;
        }
    }
}

__global__ void scatter_k(const int* __restrict__ ei, int* __restrict__ cursor,
                          int* __restrict__ col) {
    int e = blockIdx.x * 256 + threadIdx.x;
    if (e < EE) {
        int s = ei[e], d = ei[EE + e];
        if (s != d) { int p = atomicAdd(&cursor[d], 1); col[p] = s; }
    }
}

// ---------------- GEMM (h = x @ W) + per-node attention scalars ----------------
// Register-blocked: 256 threads, each computes a 4-node x 4-col tile (acc[4][4]).
// Per k: 4 ds_read_b128 (W rows, lane-spread) + 4 ds_read_b128 (x, broadcast)
// feed 64 fmas -> VALU-bound. W fully staged; X staged in K-chunks of 64.

template<int K, int M, int H, int NPB>
__global__ __launch_bounds__(256) void gemm_tile(const float* __restrict__ xin,
                          const float* __restrict__ W,
                          const float* __restrict__ att,
                          float* __restrict__ hbuf,
                          float* __restrict__ sdst, float* __restrict__ ssrc) {
    constexpr int C   = M / H;
    constexpr int MG  = M / 4;               // col-groups (4 cols per thread)
    constexpr int NG  = NPB / 4;             // node-groups (4 nodes per thread)
    static_assert(MG * NG == 256, "tile mismatch");
    constexpr int K4  = K / 4;
    constexpr int KC4 = (K4 > 16) ? 16 : K4; // staged x chunk: 16 float4 = 64 k's
    constexpr int NCH = K4 / KC4;

    __shared__ float4 Wq[K * MG];            // Wq[k*MG+mg] = W[k][4mg..4mg+3]
    __shared__ float4 Xq[NPB * KC4];         // Xq[n*KC4+k4l] = x[node0+n][...]

    int tid = threadIdx.x;
    const float4* W4 = (const float4*)W;     // W row-major [K][M] -> same flat quads
    for (int i = tid; i < K * MG; i += 256) Wq[i] = W4[i];

    int node0 = blockIdx.x * NPB;
    const float4* x4 = (const float4*)xin;

    int mg = tid % MG, ng = tid / MG;
    int nb = ng * 4;
    float acc[4][4];
    #pragma unroll
    for (int i = 0; i < 4; ++i)
        #pragma unroll
        for (int j = 0; j < 4; ++j) acc[i][j] = 0.f;

    for (int ch = 0; ch < NCH; ++ch) {
        __syncthreads();
        for (int i = tid; i < NPB * KC4; i += 256) {
            int n = i / KC4, k4l = i % KC4;
            int node = node0 + n;
            float4 v = make_float4(0.f, 0.f, 0.f, 0.f);
            if (node < NN) v = x4[(size_t)node * K4 + ch * KC4 + k4l];
            Xq[i] = v;
        }
        __syncthreads();
        #pragma unroll 4
        for (int k4 = 0; k4 < KC4; ++k4) {
            float4 xv[4], wv[4];
            #pragma unroll
            for (int i = 0; i < 4; ++i) xv[i] = Xq[(nb + i) * KC4 + k4];
            int kbase = (ch * KC4 + k4) * 4;
            #pragma unroll
            for (int kk = 0; kk < 4; ++kk) wv[kk] = Wq[(kbase + kk) * MG + mg];
            #pragma unroll
            for (int i = 0; i < 4; ++i) {
                const float* xf = (const float*)&xv[i];
                #pragma unroll
                for (int kk = 0; kk < 4; ++kk) {
                    const float* wf = (const float*)&wv[kk];
                    float xs = xf[kk];
                    acc[i][0] = fmaf(xs, wf[0], acc[i][0]);
                    acc[i][1] = fmaf(xs, wf[1], acc[i][1]);
                    acc[i][2] = fmaf(xs, wf[2], acc[i][2]);
                    acc[i][3] = fmaf(xs, wf[3], acc[i][3]);
                }
            }
        }
    }

    // epilogue: h store + attention scalars
    constexpr int TPH = C / 4;               // threads covering one head's cols
    int head = mg / TPH;
    int c0   = (mg % TPH) * 4;
    float ad[4], as_[4];
    #pragma unroll
    for (int j = 0; j < 4; ++j) {
        ad[j]  = att[head * 2 * C + c0 + j];
        as_[j] = att[head * 2 * C + C + c0 + j];
    }
    #pragma unroll
    for (int i = 0; i < 4; ++i) {
        int node = node0 + nb + i;
        if (node < NN)
            ((float4*)hbuf)[(size_t)node * MG + mg] =
                make_float4(acc[i][0], acc[i][1], acc[i][2], acc[i][3]);
        float pd = acc[i][0]*ad[0]  + acc[i][1]*ad[1]  + acc[i][2]*ad[2]  + acc[i][3]*ad[3];
        float ps = acc[i][0]*as_[0] + acc[i][1]*as_[1] + acc[i][2]*as_[2] + acc[i][3]*as_[3];
        #pragma unroll
        for (int off = 1; off < TPH; off <<= 1) {
            pd += __shfl_xor(pd, off, 64);
            ps += __shfl_xor(ps, off, 64);
        }
        if ((mg % TPH) == 0 && node < NN) {
            sdst[node * H + head] = pd;
            ssrc[node * H + head] = ps;
        }
    }
}

// ---------------- Aggregation: one wave per node, 8-edge unroll ----------------
// Exp lanes: lane = g*H + h handles edge-slot g, head h (64 lanes exactly at H=8).
// Gathers: G = 64/CT slots per instr; NL = 8/G independent row-gathers in flight.

template<int CT, int H, bool ELU_OUT>
__global__ __launch_bounds__(256) void agg_k(const int* __restrict__ rowptr, const int* __restrict__ col,
                      const float* __restrict__ sdst, const float* __restrict__ ssrc,
                      const float* __restrict__ hbuf, const float* __restrict__ bias,
                      float* __restrict__ output) {
    constexpr int C  = CT / H;
    constexpr int G  = 64 / CT;         // edge slots per gather instruction (1 or 2)
    constexpr int U  = 8;               // edge unroll
    constexpr int NL = U / G;           // row gathers per lane per iteration
    int lane = threadIdx.x & 63;
    int node = blockIdx.x * (blockDim.x >> 6) + (threadIdx.x >> 6);
    if (node >= NN) return;

    int c  = lane % CT;                 // channel handled by this lane
    int p  = lane / CT;                 // gather slot (0..G-1)
    int hh = c / C;                     // head of channel c
    int h  = lane % H;                  // head for exp lanes
    int g  = lane / H;                  // edge slot for exp lanes (valid when lane < U*H)
    float sd = (lane < U * H) ? sdst[node * H + h] : 0.f;

    int start = rowptr[node], end = rowptr[node + 1];
    float acc = 0.f, dsum = 0.f;

    int j = start;
    for (; j + U <= end; j += U) {
        float e = 0.f;
        if (lane < U * H) {
            int sg = col[j + g];
            float a = sd + ssrc[sg * H + h];
            a = (a >= 0.f) ? a : 0.2f * a;      // leaky_relu
            e = __expf(a);
            dsum += e;
        }
        float hv[NL];
        #pragma unroll
        for (int t = 0; t < NL; ++t) {
            int se = col[j + t * G + p];
            hv[t] = hbuf[(size_t)se * CT + c];
        }
        #pragma unroll
        for (int t = 0; t < NL; ++t) {
            int eidx = t * G + p;
            float ex = __shfl(e, eidx * H + hh, 64);
            acc = fmaf(ex, hv[t], acc);
        }
    }
    // remainder edges + fresh self-loop, one at a time on slot 0
    int rem = end - j;
    for (int r = 0; r <= rem; ++r) {
        int s = (r == rem) ? node : col[j + r];
        float e = 0.f;
        if (lane < H) {
            float a = sd + ssrc[s * H + h];
            a = (a >= 0.f) ? a : 0.2f * a;
            e = __expf(a);
            dsum += e;
        }
        float ex = __shfl(e, hh, 64);
        if (p == 0) acc = fmaf(ex, hbuf[(size_t)s * CT + c], acc);
    }
    // reduce dsum over edge slots: lane (g*H + h) -> sum over g
    #pragma unroll
    for (int off = H; off < U * H; off <<= 1) dsum += __shfl_xor(dsum, off, 64);
    float den = __shfl(dsum, hh, 64);
    // reduce acc over gather slots
    if (G == 2) acc += __shfl_xor(acc, 32, 64);
    if (lane < CT) {
        float v = acc / den + bias[c];
        if (ELU_OUT) v = (v > 0.f) ? v : expm1f(v);     // ELU(alpha=1)
        output[(size_t)node * CT + c] = v;
    }
}

// ---------------- launch ----------------

extern "C" void kernel_launch(void* const* d_in, const int* in_sizes, int n_in,
                              void* d_out, int out_size, void* d_ws, size_t ws_size,
                              hipStream_t stream) {
    const float* x    = (const float*)d_in[0];
    const int*   ei   = (const int*)d_in[1];
    const float* W1   = (const float*)d_in[2];
    const float* att1 = (const float*)d_in[3];
    const float* b1   = (const float*)d_in[4];
    const float* W2   = (const float*)d_in[5];
    const float* att2 = (const float*)d_in[6];
    const float* b2   = (const float*)d_in[7];
    const float* W3   = (const float*)d_in[8];
    const float* att3 = (const float*)d_in[9];
    const float* b3   = (const float*)d_in[10];
    float* out = (float*)d_out;

    char* p = (char*)d_ws;
    auto alloc = [&](size_t bytes) -> void* {
        void* r = (void*)p;
        p += (bytes + 255) & ~(size_t)255;
        return r;
    };
    int*   rowptr   = (int*)alloc((NN + 1) * sizeof(int));
    int*   cursor   = (int*)alloc(NN * sizeof(int));
    int*   partials = (int*)alloc(NB_SCAN * sizeof(int));
    int*   col      = (int*)alloc(EE * sizeof(int));
    float* sdst     = (float*)alloc((size_t)NN * 8 * sizeof(float));
    float* ssrc     = (float*)alloc((size_t)NN * 8 * sizeof(float));
    float* Hb       = (float*)alloc((size_t)NN * 64 * sizeof(float));
    float* Fb       = (float*)alloc((size_t)NN * 64 * sizeof(float));

    // --- CSR build (dst-grouped, original non-self edges only) ---
    zero_int<<<(NN + 255) / 256, 256, 0, stream>>>(cursor, NN);
    hist_k<<<EE / 256, 256, 0, stream>>>(ei, cursor);
    sum_blocks<<<NB_SCAN, 256, 0, stream>>>(cursor, partials);
    scan_partials<<<1, 128, 0, stream>>>(partials);
    scan_final<<<NB_SCAN, 256, 0, stream>>>(cursor, partials, rowptr, cursor);
    scatter_k<<<EE / 256, 256, 0, stream>>>(ei, cursor, col);

    // --- Layer 1: x[N,128] -> h[N,64]; H=8, C=8; ELU out -> Fb ---
    gemm_tile<128, 64, 8, 64><<<(NN + 63) / 64, 256, 0, stream>>>(x, W1, att1, Hb, sdst, ssrc);
    agg_k<64, 8, true><<<(NN + 3) / 4, 256, 0, stream>>>(rowptr, col, sdst, ssrc, Hb, b1, Fb);

    // --- Layer 2: Fb[N,64] -> h[N,64]; H=8, C=8; ELU out -> Fb ---
    gemm_tile<64, 64, 8, 64><<<(NN + 63) / 64, 256, 0, stream>>>(Fb, W2, att2, Hb, sdst, ssrc);
    agg_k<64, 8, true><<<(NN + 3) / 4, 256, 0, stream>>>(rowptr, col, sdst, ssrc, Hb, b2, Fb);

    // --- Layer 3: Fb[N,64] -> h[N,32]; H=1, C=32; no ELU, f32 out -> d_out ---
    gemm_tile<64, 32, 1, 128><<<(NN + 127) / 128, 256, 0, stream>>>(Fb, W3, att3, Hb, sdst, ssrc);
    agg_k<32, 1, false><<<(NN + 3) / 4, 256, 0, stream>>>(rowptr, col, sdst, ssrc, Hb, b3, out);
}

// Round 5
// 632.084 us; speedup vs baseline: 1.8025x; 1.0738x over previous
//
#include <hip/hip_runtime.h>
#include <hip/hip_bf16.h>

#define NN 100000
#define EE 1600000

constexpr int SCAN_BLK = 1024;                       // elements per scan block (256 thr * 4)
constexpr int NB_SCAN  = (NN + SCAN_BLK - 1) / SCAN_BLK;  // 98

// Range-partitioned CSR build: 8 dst-ranges (one per XCD via blockIdx%8)
constexpr int NR  = 8;
constexpr int RS  = NN / NR;        // 12500 nodes per range
constexpr int CB  = 200;            // edge chunks
constexpr int CE  = EE / CB;        // 8000 edges per chunk (exact)

// ---------------- CSR build ----------------

__global__ void zero_int(int* __restrict__ p, int n) {
    int i = blockIdx.x * 256 + threadIdx.x;
    if (i < n) p[i] = 0;
}

// blockIdx = chunk*NR + r : block handles edges [chunk*CE, (chunk+1)*CE),
// keeps only dst in [r*RS, (r+1)*RS). Writes confined to one XCD's L2 slice.
__global__ __launch_bounds__(256) void hist_k(const int* __restrict__ ei, int* __restrict__ deg) {
    int r = blockIdx.x % NR, chunk = blockIdx.x / NR;
    int lo = r * RS, hi = lo + RS;
    const int* __restrict__ dstp = ei + EE;
    int base = chunk * CE;
    for (int i = base + threadIdx.x; i < base + CE; i += 256) {
        int d = dstp[i];
        if (d >= lo && d < hi) {
            int s = ei[i];
            if (s != d) atomicAdd(&deg[d], 1);   // original self-loops masked out
        }
    }
}

__global__ void sum_blocks(const int* __restrict__ deg, int* __restrict__ partials) {
    __shared__ int sh[256];
    int t = threadIdx.x;
    int base = blockIdx.x * SCAN_BLK + t * 4;
    int s = 0;
    #pragma unroll
    for (int k = 0; k < 4; ++k) { int i = base + k; if (i < NN) s += deg[i]; }
    sh[t] = s; __syncthreads();
    for (int off = 128; off > 0; off >>= 1) {
        if (t < off) sh[t] += sh[t + off];
        __syncthreads();
    }
    if (t == 0) partials[blockIdx.x] = sh[0];
}

__global__ void scan_partials(int* __restrict__ partials) {
    __shared__ int sh[128];
    int t = threadIdx.x;
    int v = (t < NB_SCAN) ? partials[t] : 0;
    sh[t] = v;
    __syncthreads();
    for (int off = 1; off < 128; off <<= 1) {
        int tmp = (t >= off) ? sh[t - off] : 0;
        __syncthreads();
        sh[t] += tmp;
        __syncthreads();
    }
    if (t < NB_SCAN) partials[t] = sh[t] - v;   // exclusive prefix
}

__global__ void scan_final(const int* __restrict__ deg, const int* __restrict__ partials,
                           int* __restrict__ rowptr, int* __restrict__ cursor) {
    __shared__ int sh[256];
    int t = threadIdx.x;
    int base = blockIdx.x * SCAN_BLK + t * 4;
    int v[4]; int s = 0;
    #pragma unroll
    for (int k = 0; k < 4; ++k) { int i = base + k; v[k] = (i < NN) ? deg[i] : 0; s += v[k]; }
    sh[t] = s; __syncthreads();
    // Hillis-Steele inclusive scan over 256 thread sums
    for (int off = 1; off < 256; off <<= 1) {
        int tmp = (t >= off) ? sh[t - off] : 0;
        __syncthreads();
        sh[t] += tmp;
        __syncthreads();
    }
    int pref = partials[blockIdx.x] + sh[t] - s;   // exclusive prefix for this thread's chunk
    #pragma unroll
    for (int k = 0; k < 4; ++k) {
        int i = base + k;
        if (i < NN) {
            rowptr[i] = pref; cursor[i] = pref; pref += v[k];
            if (i == NN - 1) rowptr[NN] = pref;
        }
    }
}

__global__ __launch_bounds__(256) void scatter_k(const int* __restrict__ ei, int* __restrict__ cursor,
                          int* __restrict__ col) {
    int r = blockIdx.x % NR, chunk = blockIdx.x / NR;
    int lo = r * RS, hi = lo + RS;
    const int* __restrict__ dstp = ei + EE;
    int base = chunk * CE;
    for (int i = base + threadIdx.x; i < base + CE; i += 256) {
        int d = dstp[i];
        if (d >= lo && d < hi) {
            int s = ei[i];
            if (s != d) { int p = atomicAdd(&cursor[d], 1); col[p] = s; }
        }
    }
}

// ---------------- GEMM (h = x @ W) + per-node attention scalars ----------------
// Register-blocked: 256 threads, each computes a 4-node x 4-col tile (acc[4][4]).

template<int K, int M, int H, int NPB>
__global__ __launch_bounds__(256) void gemm_tile(const float* __restrict__ xin,
                          const float* __restrict__ W,
                          const float* __restrict__ att,
                          float* __restrict__ hbuf,
                          float* __restrict__ sdst, float* __restrict__ ssrc) {
    constexpr int C   = M / H;
    constexpr int MG  = M / 4;               // col-groups (4 cols per thread)
    constexpr int NG  = NPB / 4;             // node-groups (4 nodes per thread)
    static_assert(MG * NG == 256, "tile mismatch");
    constexpr int K4  = K / 4;
    constexpr int KC4 = (K4 > 16) ? 16 : K4; // staged x chunk: 16 float4 = 64 k's
    constexpr int NCH = K4 / KC4;

    __shared__ float4 Wq[K * MG];            // Wq[k*MG+mg] = W[k][4mg..4mg+3]
    __shared__ float4 Xq[NPB * KC4];         // Xq[n*KC4+k4l] = x[node0+n][...]

    int tid = threadIdx.x;
    const float4* W4 = (const float4*)W;     // W row-major [K][M] -> same flat quads
    for (int i = tid; i < K * MG; i += 256) Wq[i] = W4[i];

    int node0 = blockIdx.x * NPB;
    const float4* x4 = (const float4*)xin;

    int mg = tid % MG, ng = tid / MG;
    int nb = ng * 4;
    float acc[4][4];
    #pragma unroll
    for (int i = 0; i < 4; ++i)
        #pragma unroll
        for (int j = 0; j < 4; ++j) acc[i][j] = 0.f;

    for (int ch = 0; ch < NCH; ++ch) {
        __syncthreads();
        for (int i = tid; i < NPB * KC4; i += 256) {
            int n = i / KC4, k4l = i % KC4;
            int node = node0 + n;
            float4 v = make_float4(0.f, 0.f, 0.f, 0.f);
            if (node < NN) v = x4[(size_t)node * K4 + ch * KC4 + k4l];
            Xq[i] = v;
        }
        __syncthreads();
        #pragma unroll 4
        for (int k4 = 0; k4 < KC4; ++k4) {
            float4 xv[4], wv[4];
            #pragma unroll
            for (int i = 0; i < 4; ++i) xv[i] = Xq[(nb + i) * KC4 + k4];
            int kbase = (ch * KC4 + k4) * 4;
            #pragma unroll
            for (int kk = 0; kk < 4; ++kk) wv[kk] = Wq[(kbase + kk) * MG + mg];
            #pragma unroll
            for (int i = 0; i < 4; ++i) {
                const float* xf = (const float*)&xv[i];
                #pragma unroll
                for (int kk = 0; kk < 4; ++kk) {
                    const float* wf = (const float*)&wv[kk];
                    float xs = xf[kk];
                    acc[i][0] = fmaf(xs, wf[0], acc[i][0]);
                    acc[i][1] = fmaf(xs, wf[1], acc[i][1]);
                    acc[i][2] = fmaf(xs, wf[2], acc[i][2]);
                    acc[i][3] = fmaf(xs, wf[3], acc[i][3]);
                }
            }
        }
    }

    // epilogue: h store + attention scalars
    constexpr int TPH = C / 4;               // threads covering one head's cols
    int head = mg / TPH;
    int c0   = (mg % TPH) * 4;
    float ad[4], as_[4];
    #pragma unroll
    for (int j = 0; j < 4; ++j) {
        ad[j]  = att[head * 2 * C + c0 + j];
        as_[j] = att[head * 2 * C + C + c0 + j];
    }
    #pragma unroll
    for (int i = 0; i < 4; ++i) {
        int node = node0 + nb + i;
        if (node < NN)
            ((float4*)hbuf)[(size_t)node * MG + mg] =
                make_float4(acc[i][0], acc[i][1], acc[i][2], acc[i][3]);
        float pd = acc[i][0]*ad[0]  + acc[i][1]*ad[1]  + acc[i][2]*ad[2]  + acc[i][3]*ad[3];
        float ps = acc[i][0]*as_[0] + acc[i][1]*as_[1] + acc[i][2]*as_[2] + acc[i][3]*as_[3];
        #pragma unroll
        for (int off = 1; off < TPH; off <<= 1) {
            pd += __shfl_xor(pd, off, 64);
            ps += __shfl_xor(ps, off, 64);
        }
        if ((mg % TPH) == 0 && node < NN) {
            sdst[node * H + head] = pd;
            ssrc[node * H + head] = ps;
        }
    }
}

// ---------------- Aggregation: one wave per node, 8-edge unroll ----------------

template<int CT, int H, bool ELU_OUT>
__global__ __launch_bounds__(256) void agg_k(const int* __restrict__ rowptr, const int* __restrict__ col,
                      const float* __restrict__ sdst, const float* __restrict__ ssrc,
                      const float* __restrict__ hbuf, const float* __restrict__ bias,
                      float* __restrict__ output) {
    constexpr int C  = CT / H;
    constexpr int G  = 64 / CT;         // edge slots per gather instruction (1 or 2)
    constexpr int U  = 8;               // edge unroll
    constexpr int NL = U / G;           // row gathers per lane per iteration
    int lane = threadIdx.x & 63;
    int node = blockIdx.x * (blockDim.x >> 6) + (threadIdx.x >> 6);
    if (node >= NN) return;

    int c  = lane % CT;                 // channel handled by this lane
    int p  = lane / CT;                 // gather slot (0..G-1)
    int hh = c / C;                     // head of channel c
    int h  = lane % H;                  // head for exp lanes
    int g  = lane / H;                  // edge slot for exp lanes (valid when lane < U*H)
    float sd = (lane < U * H) ? sdst[node * H + h] : 0.f;

    int start = rowptr[node], end = rowptr[node + 1];
    float acc = 0.f, dsum = 0.f;

    int j = start;
    for (; j + U <= end; j += U) {
        float e = 0.f;
        if (lane < U * H) {
            int sg = col[j + g];
            float a = sd + ssrc[sg * H + h];
            a = (a >= 0.f) ? a : 0.2f * a;      // leaky_relu
            e = __expf(a);
            dsum += e;
        }
        float hv[NL];
        #pragma unroll
        for (int t = 0; t < NL; ++t) {
            int se = col[j + t * G + p];
            hv[t] = hbuf[(size_t)se * CT + c];
        }
        #pragma unroll
        for (int t = 0; t < NL; ++t) {
            int eidx = t * G + p;
            float ex = __shfl(e, eidx * H + hh, 64);
            acc = fmaf(ex, hv[t], acc);
        }
    }
    // remainder edges + fresh self-loop, one at a time on slot 0
    int rem = end - j;
    for (int r = 0; r <= rem; ++r) {
        int s = (r == rem) ? node : col[j + r];
        float e = 0.f;
        if (lane < H) {
            float a = sd + ssrc[s * H + h];
            a = (a >= 0.f) ? a : 0.2f * a;
            e = __expf(a);
            dsum += e;
        }
        float ex = __shfl(e, hh, 64);
        if (p == 0) acc = fmaf(ex, hbuf[(size_t)s * CT + c], acc);
    }
    // reduce dsum over edge slots: lane (g*H + h) -> sum over g
    #pragma unroll
    for (int off = H; off < U * H; off <<= 1) dsum += __shfl_xor(dsum, off, 64);
    float den = __shfl(dsum, hh, 64);
    // reduce acc over gather slots
    if (G == 2) acc += __shfl_xor(acc, 32, 64);
    if (lane < CT) {
        float v = acc / den + bias[c];
        if (ELU_OUT) v = (v > 0.f) ? v : expm1f(v);     // ELU(alpha=1)
        output[(size_t)node * CT + c] = v;
    }
}

// ---------------- launch ----------------

extern "C" void kernel_launch(void* const* d_in, const int* in_sizes, int n_in,
                              void* d_out, int out_size, void* d_ws, size_t ws_size,
                              hipStream_t stream) {
    const float* x    = (const float*)d_in[0];
    const int*   ei   = (const int*)d_in[1];
    const float* W1   = (const float*)d_in[2];
    const float* att1 = (const float*)d_in[3];
    const float* b1   = (const float*)d_in[4];
    const float* W2   = (const float*)d_in[5];
    const float* att2 = (const float*)d_in[6];
    const float* b2   = (const float*)d_in[7];
    const float* W3   = (const float*)d_in[8];
    const float* att3 = (const float*)d_in[9];
    const float* b3   = (const float*)d_in[10];
    float* out = (float*)d_out;

    char* p = (char*)d_ws;
    auto alloc = [&](size_t bytes) -> void* {
        void* r = (void*)p;
        p += (bytes + 255) & ~(size_t)255;
        return r;
    };
    int*   rowptr   = (int*)alloc((NN + 1) * sizeof(int));
    int*   cursor   = (int*)alloc(NN * sizeof(int));
    int*   partials = (int*)alloc(NB_SCAN * sizeof(int));
    int*   col      = (int*)alloc(EE * sizeof(int));
    float* sdst     = (float*)alloc((size_t)NN * 8 * sizeof(float));
    float* ssrc     = (float*)alloc((size_t)NN * 8 * sizeof(float));
    float* Hb       = (float*)alloc((size_t)NN * 64 * sizeof(float));
    float* Fb       = (float*)alloc((size_t)NN * 64 * sizeof(float));

    // --- CSR build (dst-grouped, original non-self edges only) ---
    zero_int<<<(NN + 255) / 256, 256, 0, stream>>>(cursor, NN);
    hist_k<<<CB * NR, 256, 0, stream>>>(ei, cursor);
    sum_blocks<<<NB_SCAN, 256, 0, stream>>>(cursor, partials);
    scan_partials<<<1, 128, 0, stream>>>(partials);
    scan_final<<<NB_SCAN, 256, 0, stream>>>(cursor, partials, rowptr, cursor);
    scatter_k<<<CB * NR, 256, 0, stream>>>(ei, cursor, col);

    // --- Layer 1: x[N,128] -> h[N,64]; H=8, C=8; ELU out -> Fb ---
    gemm_tile<128, 64, 8, 64><<<(NN + 63) / 64, 256, 0, stream>>>(x, W1, att1, Hb, sdst, ssrc);
    agg_k<64, 8, true><<<(NN + 3) / 4, 256, 0, stream>>>(rowptr, col, sdst, ssrc, Hb, b1, Fb);

    // --- Layer 2: Fb[N,64] -> h[N,64]; H=8, C=8; ELU out -> Fb ---
    gemm_tile<64, 64, 8, 64><<<(NN + 63) / 64, 256, 0, stream>>>(Fb, W2, att2, Hb, sdst, ssrc);
    agg_k<64, 8, true><<<(NN + 3) / 4, 256, 0, stream>>>(rowptr, col, sdst, ssrc, Hb, b2, Fb);

    // --- Layer 3: Fb[N,64] -> h[N,32]; H=1, C=32; no ELU, f32 out -> d_out ---
    gemm_tile<64, 32, 1, 128><<<(NN + 127) / 128, 256, 0, stream>>>(Fb, W3, att3, Hb, sdst, ssrc);
    agg_k<32, 1, false><<<(NN + 3) / 4, 256, 0, stream>>>(rowptr, col, sdst, ssrc, Hb, b3, out);
}

// Round 6
// 597.797 us; speedup vs baseline: 1.9059x; 1.0574x over previous
//
#include <hip/hip_runtime.h>
#include <hip/hip_bf16.h>

#define NN 100000
#define EE 1600000

constexpr int SCAN_BLK = 1024;                       // elements per scan block (256 thr * 4)
constexpr int NB_SCAN  = (NN + SCAN_BLK - 1) / SCAN_BLK;  // 98

// Range-partitioned CSR build: 8 dst-ranges (one per XCD via blockIdx%8)
constexpr int NR  = 8;
constexpr int RS  = NN / NR;        // 12500 nodes per range
constexpr int CB  = 200;            // edge chunks
constexpr int CE  = EE / CB;        // 8000 edges per chunk (exact)

// ---------------- CSR build ----------------

__global__ void zero_int(int* __restrict__ p, int n) {
    int i = blockIdx.x * 256 + threadIdx.x;
    if (i < n) p[i] = 0;
}

// blockIdx = chunk*NR + r : block handles edges [chunk*CE, (chunk+1)*CE),
// keeps only dst in [r*RS, (r+1)*RS). Writes confined to one XCD's L2 slice.
__global__ __launch_bounds__(256) void hist_k(const int* __restrict__ ei, int* __restrict__ deg) {
    int r = blockIdx.x % NR, chunk = blockIdx.x / NR;
    int lo = r * RS, hi = lo + RS;
    const int* __restrict__ dstp = ei + EE;
    int base = chunk * CE;
    for (int i = base + threadIdx.x; i < base + CE; i += 256) {
        int d = dstp[i];
        if (d >= lo && d < hi) {
            int s = ei[i];
            if (s != d) atomicAdd(&deg[d], 1);   // original self-loops masked out
        }
    }
}

__global__ void sum_blocks(const int* __restrict__ deg, int* __restrict__ partials) {
    __shared__ int sh[256];
    int t = threadIdx.x;
    int base = blockIdx.x * SCAN_BLK + t * 4;
    int s = 0;
    #pragma unroll
    for (int k = 0; k < 4; ++k) { int i = base + k; if (i < NN) s += deg[i]; }
    sh[t] = s; __syncthreads();
    for (int off = 128; off > 0; off >>= 1) {
        if (t < off) sh[t] += sh[t + off];
        __syncthreads();
    }
    if (t == 0) partials[blockIdx.x] = sh[0];
}

__global__ void scan_partials(int* __restrict__ partials) {
    __shared__ int sh[128];
    int t = threadIdx.x;
    int v = (t < NB_SCAN) ? partials[t] : 0;
    sh[t] = v;
    __syncthreads();
    for (int off = 1; off < 128; off <<= 1) {
        int tmp = (t >= off) ? sh[t - off] : 0;
        __syncthreads();
        sh[t] += tmp;
        __syncthreads();
    }
    if (t < NB_SCAN) partials[t] = sh[t] - v;   // exclusive prefix
}

__global__ void scan_final(const int* __restrict__ deg, const int* __restrict__ partials,
                           int* __restrict__ rowptr, int* __restrict__ cursor) {
    __shared__ int sh[256];
    int t = threadIdx.x;
    int base = blockIdx.x * SCAN_BLK + t * 4;
    int v[4]; int s = 0;
    #pragma unroll
    for (int k = 0; k < 4; ++k) { int i = base + k; v[k] = (i < NN) ? deg[i] : 0; s += v[k]; }
    sh[t] = s; __syncthreads();
    // Hillis-Steele inclusive scan over 256 thread sums
    for (int off = 1; off < 256; off <<= 1) {
        int tmp = (t >= off) ? sh[t - off] : 0;
        __syncthreads();
        sh[t] += tmp;
        __syncthreads();
    }
    int pref = partials[blockIdx.x] + sh[t] - s;   // exclusive prefix for this thread's chunk
    #pragma unroll
    for (int k = 0; k < 4; ++k) {
        int i = base + k;
        if (i < NN) {
            rowptr[i] = pref; cursor[i] = pref; pref += v[k];
            if (i == NN - 1) rowptr[NN] = pref;
        }
    }
}

__global__ __launch_bounds__(256) void scatter_k(const int* __restrict__ ei, int* __restrict__ cursor,
                          int* __restrict__ col) {
    int r = blockIdx.x % NR, chunk = blockIdx.x / NR;
    int lo = r * RS, hi = lo + RS;
    const int* __restrict__ dstp = ei + EE;
    int base = chunk * CE;
    for (int i = base + threadIdx.x; i < base + CE; i += 256) {
        int d = dstp[i];
        if (d >= lo && d < hi) {
            int s = ei[i];
            if (s != d) { int p = atomicAdd(&cursor[d], 1); col[p] = s; }
        }
    }
}

// ---------------- GEMM (h = x @ W) + per-node attention scalars ----------------
// Register-blocked: 256 threads, each computes a 4-node x 4-col tile (acc[4][4]).
// h written to hbuf as packed bf16 (halves agg gather traffic).

template<int K, int M, int H, int NPB>
__global__ __launch_bounds__(256) void gemm_tile(const float* __restrict__ xin,
                          const float* __restrict__ W,
                          const float* __restrict__ att,
                          unsigned short* __restrict__ hbuf,
                          float* __restrict__ sdst, float* __restrict__ ssrc) {
    constexpr int C   = M / H;
    constexpr int MG  = M / 4;               // col-groups (4 cols per thread)
    constexpr int NG  = NPB / 4;             // node-groups (4 nodes per thread)
    static_assert(MG * NG == 256, "tile mismatch");
    constexpr int K4  = K / 4;
    constexpr int KC4 = (K4 > 16) ? 16 : K4; // staged x chunk: 16 float4 = 64 k's
    constexpr int NCH = K4 / KC4;

    __shared__ float4 Wq[K * MG];            // Wq[k*MG+mg] = W[k][4mg..4mg+3]
    __shared__ float4 Xq[NPB * KC4];         // Xq[n*KC4+k4l] = x[node0+n][...]

    int tid = threadIdx.x;
    const float4* W4 = (const float4*)W;     // W row-major [K][M] -> same flat quads
    for (int i = tid; i < K * MG; i += 256) Wq[i] = W4[i];

    int node0 = blockIdx.x * NPB;
    const float4* x4 = (const float4*)xin;

    int mg = tid % MG, ng = tid / MG;
    int nb = ng * 4;
    float acc[4][4];
    #pragma unroll
    for (int i = 0; i < 4; ++i)
        #pragma unroll
        for (int j = 0; j < 4; ++j) acc[i][j] = 0.f;

    for (int ch = 0; ch < NCH; ++ch) {
        __syncthreads();
        for (int i = tid; i < NPB * KC4; i += 256) {
            int n = i / KC4, k4l = i % KC4;
            int node = node0 + n;
            float4 v = make_float4(0.f, 0.f, 0.f, 0.f);
            if (node < NN) v = x4[(size_t)node * K4 + ch * KC4 + k4l];
            Xq[i] = v;
        }
        __syncthreads();
        #pragma unroll 4
        for (int k4 = 0; k4 < KC4; ++k4) {
            float4 xv[4], wv[4];
            #pragma unroll
            for (int i = 0; i < 4; ++i) xv[i] = Xq[(nb + i) * KC4 + k4];
            int kbase = (ch * KC4 + k4) * 4;
            #pragma unroll
            for (int kk = 0; kk < 4; ++kk) wv[kk] = Wq[(kbase + kk) * MG + mg];
            #pragma unroll
            for (int i = 0; i < 4; ++i) {
                const float* xf = (const float*)&xv[i];
                #pragma unroll
                for (int kk = 0; kk < 4; ++kk) {
                    const float* wf = (const float*)&wv[kk];
                    float xs = xf[kk];
                    acc[i][0] = fmaf(xs, wf[0], acc[i][0]);
                    acc[i][1] = fmaf(xs, wf[1], acc[i][1]);
                    acc[i][2] = fmaf(xs, wf[2], acc[i][2]);
                    acc[i][3] = fmaf(xs, wf[3], acc[i][3]);
                }
            }
        }
    }

    // epilogue: packed-bf16 h store + attention scalars (f32)
    constexpr int TPH = C / 4;               // threads covering one head's cols
    int head = mg / TPH;
    int c0   = (mg % TPH) * 4;
    float ad[4], as_[4];
    #pragma unroll
    for (int j = 0; j < 4; ++j) {
        ad[j]  = att[head * 2 * C + c0 + j];
        as_[j] = att[head * 2 * C + C + c0 + j];
    }
    #pragma unroll
    for (int i = 0; i < 4; ++i) {
        int node = node0 + nb + i;
        if (node < NN) {
            unsigned short us[4];
            #pragma unroll
            for (int j = 0; j < 4; ++j) {
                __hip_bfloat16 b = __float2bfloat16(acc[i][j]);
                us[j] = *(unsigned short*)&b;
            }
            uint2 pk;
            pk.x = (unsigned)us[0] | ((unsigned)us[1] << 16);
            pk.y = (unsigned)us[2] | ((unsigned)us[3] << 16);
            ((uint2*)hbuf)[(size_t)node * MG + mg] = pk;
        }
        float pd = acc[i][0]*ad[0]  + acc[i][1]*ad[1]  + acc[i][2]*ad[2]  + acc[i][3]*ad[3];
        float ps = acc[i][0]*as_[0] + acc[i][1]*as_[1] + acc[i][2]*as_[2] + acc[i][3]*as_[3];
        #pragma unroll
        for (int off = 1; off < TPH; off <<= 1) {
            pd += __shfl_xor(pd, off, 64);
            ps += __shfl_xor(ps, off, 64);
        }
        if ((mg % TPH) == 0 && node < NN) {
            sdst[node * H + head] = pd;
            ssrc[node * H + head] = ps;
        }
    }
}

// ---------------- Aggregation: one wave per node, fully-masked 8-edge loop ----
// Work list per node = CSR edges [start,end) + virtual self-loop at index 'end'.
// All iterations are 8-wide; invalid slots contribute e=0 (gather clamped to node).
// hbuf is bf16: each lane loads one uint = 2 channels; CP=CT/2 lanes per row,
// G=64/CP edge slots per gather instruction, NL=8/G gathers in flight per lane.

template<int CT, int H, bool ELU_OUT>
__global__ __launch_bounds__(256) void agg_k(const int* __restrict__ rowptr, const int* __restrict__ col,
                      const float* __restrict__ sdst, const float* __restrict__ ssrc,
                      const unsigned short* __restrict__ hbuf, const float* __restrict__ bias,
                      float* __restrict__ output) {
    constexpr int C  = CT / H;          // channels per head
    constexpr int CP = CT / 2;          // lanes covering one bf16 row (pairs)
    constexpr int G  = 64 / CP;         // edge slots per gather instruction (2 or 4)
    constexpr int U  = 8;               // edge unroll
    constexpr int NL = U / G;           // row gathers per lane per iteration
    int lane = threadIdx.x & 63;
    int node = blockIdx.x * (blockDim.x >> 6) + (threadIdx.x >> 6);
    if (node >= NN) return;

    int cp = lane % CP;                 // channel pair: channels {2cp, 2cp+1}
    int pp = lane / CP;                 // gather slot parity (0..G-1)
    int hh = (2 * cp) / C;              // head of these channels
    int h  = lane % H;                  // head for exp lanes
    int g  = lane / H;                  // edge slot for exp lanes (valid when lane < U*H)
    float sd = (lane < U * H) ? sdst[node * H + h] : 0.f;

    int start = rowptr[node], end = rowptr[node + 1];
    int total = end + 1;                // + virtual self-loop at index 'end'
    const unsigned* hb = (const unsigned*)hbuf;
    float2 acc = make_float2(0.f, 0.f);
    float dsum = 0.f;

    for (int j = start; j < total; j += U) {
        float e = 0.f;
        if (lane < U * H) {
            int idx = j + g;
            if (idx < total) {
                int sg = (idx == end) ? node : col[idx];
                float a = sd + ssrc[sg * H + h];
                a = (a >= 0.f) ? a : 0.2f * a;      // leaky_relu
                e = __expf(a);
                dsum += e;
            }
        }
        unsigned hv[NL];
        #pragma unroll
        for (int t = 0; t < NL; ++t) {
            int idx = j + t * G + pp;
            int se = (idx < end) ? col[idx] : node;   // self-loop or masked -> node
            hv[t] = hb[(size_t)se * CP + cp];
        }
        #pragma unroll
        for (int t = 0; t < NL; ++t) {
            int eidx = t * G + pp;
            float ex = __shfl(e, eidx * H + hh, 64);  // 0 for masked slots
            float hx = __uint_as_float(hv[t] << 16);
            float hy = __uint_as_float(hv[t] & 0xffff0000u);
            acc.x = fmaf(ex, hx, acc.x);
            acc.y = fmaf(ex, hy, acc.y);
        }
    }
    // reduce dsum over edge slots: lane (g*H + h) -> sum over g
    #pragma unroll
    for (int off = H; off < U * H; off <<= 1) dsum += __shfl_xor(dsum, off, 64);
    float den = __shfl(dsum, hh, 64);
    // reduce acc over gather-slot parities
    #pragma unroll
    for (int off = CP; off < 64; off <<= 1) {
        acc.x += __shfl_xor(acc.x, off, 64);
        acc.y += __shfl_xor(acc.y, off, 64);
    }
    if (lane < CP) {
        float vx = acc.x / den + bias[2 * cp];
        float vy = acc.y / den + bias[2 * cp + 1];
        if (ELU_OUT) {
            vx = (vx > 0.f) ? vx : expm1f(vx);       // ELU(alpha=1)
            vy = (vy > 0.f) ? vy : expm1f(vy);
        }
        ((float2*)output)[(size_t)node * CP + cp] = make_float2(vx, vy);
    }
}

// ---------------- launch ----------------

extern "C" void kernel_launch(void* const* d_in, const int* in_sizes, int n_in,
                              void* d_out, int out_size, void* d_ws, size_t ws_size,
                              hipStream_t stream) {
    const float* x    = (const float*)d_in[0];
    const int*   ei   = (const int*)d_in[1];
    const float* W1   = (const float*)d_in[2];
    const float* att1 = (const float*)d_in[3];
    const float* b1   = (const float*)d_in[4];
    const float* W2   = (const float*)d_in[5];
    const float* att2 = (const float*)d_in[6];
    const float* b2   = (const float*)d_in[7];
    const float* W3   = (const float*)d_in[8];
    const float* att3 = (const float*)d_in[9];
    const float* b3   = (const float*)d_in[10];
    float* out = (float*)d_out;

    char* p = (char*)d_ws;
    auto alloc = [&](size_t bytes) -> void* {
        void* r = (void*)p;
        p += (bytes + 255) & ~(size_t)255;
        return r;
    };
    int*   rowptr   = (int*)alloc((NN + 1) * sizeof(int));
    int*   cursor   = (int*)alloc(NN * sizeof(int));
    int*   partials = (int*)alloc(NB_SCAN * sizeof(int));
    int*   col      = (int*)alloc(EE * sizeof(int));
    float* sdst     = (float*)alloc((size_t)NN * 8 * sizeof(float));
    float* ssrc     = (float*)alloc((size_t)NN * 8 * sizeof(float));
    unsigned short* Hb = (unsigned short*)alloc((size_t)NN * 64 * sizeof(unsigned short));
    float* Fb       = (float*)alloc((size_t)NN * 64 * sizeof(float));

    // --- CSR build (dst-grouped, original non-self edges only) ---
    zero_int<<<(NN + 255) / 256, 256, 0, stream>>>(cursor, NN);
    hist_k<<<CB * NR, 256, 0, stream>>>(ei, cursor);
    sum_blocks<<<NB_SCAN, 256, 0, stream>>>(cursor, partials);
    scan_partials<<<1, 128, 0, stream>>>(partials);
    scan_final<<<NB_SCAN, 256, 0, stream>>>(cursor, partials, rowptr, cursor);
    scatter_k<<<CB * NR, 256, 0, stream>>>(ei, cursor, col);

    // --- Layer 1: x[N,128] -> h[N,64]; H=8, C=8; ELU out -> Fb ---
    gemm_tile<128, 64, 8, 64><<<(NN + 63) / 64, 256, 0, stream>>>(x, W1, att1, Hb, sdst, ssrc);
    agg_k<64, 8, true><<<(NN + 3) / 4, 256, 0, stream>>>(rowptr, col, sdst, ssrc, Hb, b1, Fb);

    // --- Layer 2: Fb[N,64] -> h[N,64]; H=8, C=8; ELU out -> Fb ---
    gemm_tile<64, 64, 8, 64><<<(NN + 63) / 64, 256, 0, stream>>>(Fb, W2, att2, Hb, sdst, ssrc);
    agg_k<64, 8, true><<<(NN + 3) / 4, 256, 0, stream>>>(rowptr, col, sdst, ssrc, Hb, b2, Fb);

    // --- Layer 3: Fb[N,64] -> h[N,32]; H=1, C=32; no ELU, f32 out -> d_out ---
    gemm_tile<64, 32, 1, 128><<<(NN + 127) / 128, 256, 0, stream>>>(Fb, W3, att3, Hb, sdst, ssrc);
    agg_k<32, 1, false><<<(NN + 3) / 4, 256, 0, stream>>>(rowptr, col, sdst, ssrc, Hb, b3, out);
}

// Round 7
// 489.035 us; speedup vs baseline: 2.3298x; 1.2224x over previous
//
#include <hip/hip_runtime.h>
#include <hip/hip_bf16.h>

#define NN 100000
#define EE 1600000

constexpr int SCAN_BLK = 1024;                       // elements per scan block (256 thr * 4)
constexpr int NB_SCAN  = (NN + SCAN_BLK - 1) / SCAN_BLK;  // 98

// Range-partitioned CSR build: 8 dst-ranges (one per XCD via blockIdx%8)
constexpr int NR  = 8;
constexpr int RS  = NN / NR;        // 12500 nodes per range
constexpr int CB  = 200;            // edge chunks
constexpr int CE  = EE / CB;        // 8000 edges per chunk (exact)

// ---------------- CSR build ----------------

__global__ void zero_int(int* __restrict__ p, int n) {
    int i = blockIdx.x * 256 + threadIdx.x;
    if (i < n) p[i] = 0;
}

__global__ __launch_bounds__(256) void hist_k(const int* __restrict__ ei, int* __restrict__ deg) {
    int r = blockIdx.x % NR, chunk = blockIdx.x / NR;
    int lo = r * RS, hi = lo + RS;
    const int* __restrict__ dstp = ei + EE;
    int base = chunk * CE;
    for (int i = base + threadIdx.x; i < base + CE; i += 256) {
        int d = dstp[i];
        if (d >= lo && d < hi) {
            int s = ei[i];
            if (s != d) atomicAdd(&deg[d], 1);   // original self-loops masked out
        }
    }
}

__global__ void sum_blocks(const int* __restrict__ deg, int* __restrict__ partials) {
    __shared__ int sh[256];
    int t = threadIdx.x;
    int base = blockIdx.x * SCAN_BLK + t * 4;
    int s = 0;
    #pragma unroll
    for (int k = 0; k < 4; ++k) { int i = base + k; if (i < NN) s += deg[i]; }
    sh[t] = s; __syncthreads();
    for (int off = 128; off > 0; off >>= 1) {
        if (t < off) sh[t] += sh[t + off];
        __syncthreads();
    }
    if (t == 0) partials[blockIdx.x] = sh[0];
}

__global__ void scan_partials(int* __restrict__ partials) {
    __shared__ int sh[128];
    int t = threadIdx.x;
    int v = (t < NB_SCAN) ? partials[t] : 0;
    sh[t] = v;
    __syncthreads();
    for (int off = 1; off < 128; off <<= 1) {
        int tmp = (t >= off) ? sh[t - off] : 0;
        __syncthreads();
        sh[t] += tmp;
        __syncthreads();
    }
    if (t < NB_SCAN) partials[t] = sh[t] - v;   // exclusive prefix
}

__global__ void scan_final(const int* __restrict__ deg, const int* __restrict__ partials,
                           int* __restrict__ rowptr, int* __restrict__ cursor) {
    __shared__ int sh[256];
    int t = threadIdx.x;
    int base = blockIdx.x * SCAN_BLK + t * 4;
    int v[4]; int s = 0;
    #pragma unroll
    for (int k = 0; k < 4; ++k) { int i = base + k; v[k] = (i < NN) ? deg[i] : 0; s += v[k]; }
    sh[t] = s; __syncthreads();
    for (int off = 1; off < 256; off <<= 1) {
        int tmp = (t >= off) ? sh[t - off] : 0;
        __syncthreads();
        sh[t] += tmp;
        __syncthreads();
    }
    int pref = partials[blockIdx.x] + sh[t] - s;
    #pragma unroll
    for (int k = 0; k < 4; ++k) {
        int i = base + k;
        if (i < NN) {
            rowptr[i] = pref; cursor[i] = pref; pref += v[k];
            if (i == NN - 1) rowptr[NN] = pref;
        }
    }
}

__global__ __launch_bounds__(256) void scatter_k(const int* __restrict__ ei, int* __restrict__ cursor,
                          int* __restrict__ col) {
    int r = blockIdx.x % NR, chunk = blockIdx.x / NR;
    int lo = r * RS, hi = lo + RS;
    const int* __restrict__ dstp = ei + EE;
    int base = chunk * CE;
    for (int i = base + threadIdx.x; i < base + CE; i += 256) {
        int d = dstp[i];
        if (d >= lo && d < hi) {
            int s = ei[i];
            if (s != d) { int p = atomicAdd(&cursor[d], 1); col[p] = s; }
        }
    }
}

// ---------------- GEMM (h = x @ W) + per-node record ----------------
// Register-blocked 4x4 per thread. Epilogue writes an interleaved per-node
// record into Rb (stride RSU uints): [0..H) = ssrc (f32), [8..8+M/2) = h (bf16
// packed 2/uint). sdst stays a separate f32 array (only read for own node).

template<int K, int M, int H, int NPB, int RSU>
__global__ __launch_bounds__(256) void gemm_tile(const float* __restrict__ xin,
                          const float* __restrict__ W,
                          const float* __restrict__ att,
                          unsigned* __restrict__ Rb,
                          float* __restrict__ sdst) {
    constexpr int C   = M / H;
    constexpr int MG  = M / 4;               // col-groups (4 cols per thread)
    constexpr int NG  = NPB / 4;
    static_assert(MG * NG == 256, "tile mismatch");
    constexpr int K4  = K / 4;
    constexpr int KC4 = (K4 > 16) ? 16 : K4;
    constexpr int NCH = K4 / KC4;

    __shared__ float4 Wq[K * MG];
    __shared__ float4 Xq[NPB * KC4];

    int tid = threadIdx.x;
    const float4* W4 = (const float4*)W;
    for (int i = tid; i < K * MG; i += 256) Wq[i] = W4[i];

    int node0 = blockIdx.x * NPB;
    const float4* x4 = (const float4*)xin;

    int mg = tid % MG, ng = tid / MG;
    int nb = ng * 4;
    float acc[4][4];
    #pragma unroll
    for (int i = 0; i < 4; ++i)
        #pragma unroll
        for (int j = 0; j < 4; ++j) acc[i][j] = 0.f;

    for (int ch = 0; ch < NCH; ++ch) {
        __syncthreads();
        for (int i = tid; i < NPB * KC4; i += 256) {
            int n = i / KC4, k4l = i % KC4;
            int node = node0 + n;
            float4 v = make_float4(0.f, 0.f, 0.f, 0.f);
            if (node < NN) v = x4[(size_t)node * K4 + ch * KC4 + k4l];
            Xq[i] = v;
        }
        __syncthreads();
        #pragma unroll 4
        for (int k4 = 0; k4 < KC4; ++k4) {
            float4 xv[4], wv[4];
            #pragma unroll
            for (int i = 0; i < 4; ++i) xv[i] = Xq[(nb + i) * KC4 + k4];
            int kbase = (ch * KC4 + k4) * 4;
            #pragma unroll
            for (int kk = 0; kk < 4; ++kk) wv[kk] = Wq[(kbase + kk) * MG + mg];
            #pragma unroll
            for (int i = 0; i < 4; ++i) {
                const float* xf = (const float*)&xv[i];
                #pragma unroll
                for (int kk = 0; kk < 4; ++kk) {
                    const float* wf = (const float*)&wv[kk];
                    float xs = xf[kk];
                    acc[i][0] = fmaf(xs, wf[0], acc[i][0]);
                    acc[i][1] = fmaf(xs, wf[1], acc[i][1]);
                    acc[i][2] = fmaf(xs, wf[2], acc[i][2]);
                    acc[i][3] = fmaf(xs, wf[3], acc[i][3]);
                }
            }
        }
    }

    constexpr int TPH = C / 4;               // threads covering one head's cols
    int head = mg / TPH;
    int c0   = (mg % TPH) * 4;
    float ad[4], as_[4];
    #pragma unroll
    for (int j = 0; j < 4; ++j) {
        ad[j]  = att[head * 2 * C + c0 + j];
        as_[j] = att[head * 2 * C + C + c0 + j];
    }
    #pragma unroll
    for (int i = 0; i < 4; ++i) {
        int node = node0 + nb + i;
        if (node < NN) {
            unsigned short us[4];
            #pragma unroll
            for (int j = 0; j < 4; ++j) {
                __hip_bfloat16 b = __float2bfloat16(acc[i][j]);
                us[j] = *(unsigned short*)&b;
            }
            uint2 pk;
            pk.x = (unsigned)us[0] | ((unsigned)us[1] << 16);
            pk.y = (unsigned)us[2] | ((unsigned)us[3] << 16);
            *(uint2*)(Rb + (size_t)node * RSU + 8 + 2 * mg) = pk;
        }
        float pd = acc[i][0]*ad[0]  + acc[i][1]*ad[1]  + acc[i][2]*ad[2]  + acc[i][3]*ad[3];
        float ps = acc[i][0]*as_[0] + acc[i][1]*as_[1] + acc[i][2]*as_[2] + acc[i][3]*as_[3];
        #pragma unroll
        for (int off = 1; off < TPH; off <<= 1) {
            pd += __shfl_xor(pd, off, 64);
            ps += __shfl_xor(ps, off, 64);
        }
        if ((mg % TPH) == 0 && node < NN) {
            sdst[node * H + head] = pd;
            ((float*)(Rb + (size_t)node * RSU))[head] = ps;
        }
    }
}

// ---------------- Aggregation: one wave per node, U-edge masked loop ----------
// Record Rb per node (RSU uints): ssrc f32 at [0..H), h bf16-packed at [8..8+CT/2).
// Per iteration: lanes<U cooperatively load col[j..j+U); exp lanes each handle
// EPEL (edge,head) pairs; gather lanes keep NL=U/G independent record loads in
// flight. Tail and self-loop are masked slots of the last iteration.

template<int CT, int H, int U, int RSU, bool ELU_OUT>
__global__ __launch_bounds__(256) void agg_k(const int* __restrict__ rowptr, const int* __restrict__ col,
                      const float* __restrict__ sdst, const unsigned* __restrict__ Rb,
                      const float* __restrict__ bias, float* __restrict__ output) {
    constexpr int C    = CT / H;         // channels per head
    constexpr int CP   = CT / 2;         // lanes covering one packed row
    constexpr int G    = 64 / CP;        // edge slots per gather instruction
    constexpr int NL   = U / G;          // row gathers in flight per lane
    constexpr int EPEL = (U * H >= 64) ? (U * H) / 64 : 1;   // edges per exp lane
    static_assert(EPEL == 1 || EPEL == 2, "mapping");

    int lane = threadIdx.x & 63;
    int node = blockIdx.x * (blockDim.x >> 6) + (threadIdx.x >> 6);
    if (node >= NN) return;

    int cp = lane % CP;                  // channel pair {2cp, 2cp+1}
    int pp = lane / CP;                  // gather slot parity (0..G-1)
    int hh = (2 * cp) / C;               // head of these channels
    int eh = lane % H;                   // exp-lane head
    int gb = lane / H;                   // exp-lane base edge slot

    float sd = (lane < U * H) ? sdst[node * H + eh] : 0.f;

    int start = rowptr[node], end = rowptr[node + 1];
    int total = end + 1;                 // + virtual self-loop at index 'end'
    float2 acc = make_float2(0.f, 0.f);
    float dsum = 0.f;

    for (int j = start; j < total; j += U) {
        // cooperative col load: lane l<U covers list index j+l (clamped to node)
        int cv = node;
        {
            int idx = j + lane;
            if (lane < U && idx < end) cv = col[idx];
        }
        // exp lanes
        float e1 = 0.f, e2 = 0.f;
        if (EPEL == 2) {
            int b1 = __shfl(cv, gb, 64);
            int b2 = __shfl(cv, gb + U / 2, 64);
            float s1 = ((const float*)(Rb + (size_t)b1 * RSU))[eh];
            float s2 = ((const float*)(Rb + (size_t)b2 * RSU))[eh];
            float a1 = sd + s1; a1 = (a1 >= 0.f) ? a1 : 0.2f * a1;
            float a2 = sd + s2; a2 = (a2 >= 0.f) ? a2 : 0.2f * a2;
            if (j + gb < total)          e1 = __expf(a1);
            if (j + gb + U / 2 < total)  e2 = __expf(a2);
            dsum += e1 + e2;
        } else {
            if (lane < U * H) {
                float s1 = ((const float*)(Rb + (size_t)cv * RSU))[eh];
                float a1 = sd + s1; a1 = (a1 >= 0.f) ? a1 : 0.2f * a1;
                if (j + gb < total) e1 = __expf(a1);
                dsum += e1;
            }
        }
        // row gathers (independent, all issued before use)
        unsigned hv[NL];
        #pragma unroll
        for (int t = 0; t < NL; ++t) {
            int se = __shfl(cv, t * G + pp, 64);
            hv[t] = Rb[(size_t)se * RSU + 8 + cp];
        }
        #pragma unroll
        for (int t = 0; t < NL; ++t) {
            int eidx = t * G + pp;
            float ex;
            if (EPEL == 2)
                ex = __shfl((t < NL / 2) ? e1 : e2, (eidx & (U / 2 - 1)) * H + hh, 64);
            else
                ex = __shfl(e1, eidx * H + hh, 64);
            float hx = __uint_as_float(hv[t] << 16);
            float hy = __uint_as_float(hv[t] & 0xffff0000u);
            acc.x = fmaf(ex, hx, acc.x);
            acc.y = fmaf(ex, hy, acc.y);
        }
    }
    // reduce dsum over edge-slot lanes (masked lanes contribute 0)
    #pragma unroll
    for (int off = H; off < 64; off <<= 1) dsum += __shfl_xor(dsum, off, 64);
    float den = __shfl(dsum, hh, 64);    // lane 'hh' holds head hh's full sum
    // reduce acc over gather-slot parities
    #pragma unroll
    for (int off = CP; off < 64; off <<= 1) {
        acc.x += __shfl_xor(acc.x, off, 64);
        acc.y += __shfl_xor(acc.y, off, 64);
    }
    if (lane < CP) {
        float inv = 1.f / den;
        float vx = acc.x * inv + bias[2 * cp];
        float vy = acc.y * inv + bias[2 * cp + 1];
        if (ELU_OUT) {
            vx = (vx > 0.f) ? vx : expm1f(vx);       // ELU(alpha=1)
            vy = (vy > 0.f) ? vy : expm1f(vy);
        }
        ((float2*)output)[(size_t)node * CP + cp] = make_float2(vx, vy);
    }
}

// ---------------- launch ----------------

extern "C" void kernel_launch(void* const* d_in, const int* in_sizes, int n_in,
                              void* d_out, int out_size, void* d_ws, size_t ws_size,
                              hipStream_t stream) {
    const float* x    = (const float*)d_in[0];
    const int*   ei   = (const int*)d_in[1];
    const float* W1   = (const float*)d_in[2];
    const float* att1 = (const float*)d_in[3];
    const float* b1   = (const float*)d_in[4];
    const float* W2   = (const float*)d_in[5];
    const float* att2 = (const float*)d_in[6];
    const float* b2   = (const float*)d_in[7];
    const float* W3   = (const float*)d_in[8];
    const float* att3 = (const float*)d_in[9];
    const float* b3   = (const float*)d_in[10];
    float* out = (float*)d_out;

    char* p = (char*)d_ws;
    auto alloc = [&](size_t bytes) -> void* {
        void* r = (void*)p;
        p += (bytes + 255) & ~(size_t)255;
        return r;
    };
    int*   rowptr   = (int*)alloc((NN + 1) * sizeof(int));
    int*   cursor   = (int*)alloc(NN * sizeof(int));
    int*   partials = (int*)alloc(NB_SCAN * sizeof(int));
    int*   col      = (int*)alloc(EE * sizeof(int));
    float* sdst     = (float*)alloc((size_t)NN * 8 * sizeof(float));
    unsigned* Rb    = (unsigned*)alloc((size_t)NN * 48 * sizeof(unsigned));
    float* Fb       = (float*)alloc((size_t)NN * 64 * sizeof(float));

    // --- CSR build (dst-grouped, original non-self edges only) ---
    zero_int<<<(NN + 255) / 256, 256, 0, stream>>>(cursor, NN);
    hist_k<<<CB * NR, 256, 0, stream>>>(ei, cursor);
    sum_blocks<<<NB_SCAN, 256, 0, stream>>>(cursor, partials);
    scan_partials<<<1, 128, 0, stream>>>(partials);
    scan_final<<<NB_SCAN, 256, 0, stream>>>(cursor, partials, rowptr, cursor);
    scatter_k<<<CB * NR, 256, 0, stream>>>(ei, cursor, col);

    // --- Layer 1: x[N,128] -> h[N,64]; H=8, C=8; ELU out -> Fb ---
    gemm_tile<128, 64, 8, 64, 48><<<(NN + 63) / 64, 256, 0, stream>>>(x, W1, att1, Rb, sdst);
    agg_k<64, 8, 16, 48, true><<<(NN + 3) / 4, 256, 0, stream>>>(rowptr, col, sdst, Rb, b1, Fb);

    // --- Layer 2: Fb[N,64] -> h[N,64]; H=8, C=8; ELU out -> Fb ---
    gemm_tile<64, 64, 8, 64, 48><<<(NN + 63) / 64, 256, 0, stream>>>(Fb, W2, att2, Rb, sdst);
    agg_k<64, 8, 16, 48, true><<<(NN + 3) / 4, 256, 0, stream>>>(rowptr, col, sdst, Rb, b2, Fb);

    // --- Layer 3: Fb[N,64] -> h[N,32]; H=1, C=32; no ELU, f32 out -> d_out ---
    gemm_tile<64, 32, 1, 128, 32><<<(NN + 127) / 128, 256, 0, stream>>>(Fb, W3, att3, Rb, sdst);
    agg_k<32, 1, 32, 32, false><<<(NN + 3) / 4, 256, 0, stream>>>(rowptr, col, sdst, Rb, b3, out);
}